// Round 1
// baseline (423.824 us; speedup 1.0000x reference)
//
#include <hip/hip_runtime.h>
#include <hip/hip_bf16.h>
#include <math.h>

// Problem constants
#define BS 32
#define SEQ 50
#define ML 16
#define NN 15
#define NTREE (BS*SEQ*ML)     // 25600
#define NROW (BS*SEQ)         // 1600
#define VOCAB 50000
#define EMB 128
#define ENC 128
#define GH 32
#define NC 100
#define LH 128
#define LIN_D 167             // 101 + 64 + 2

// ---------------------------------------------------------------------------
// Generic fp32 GEMM: C[M][N] = A[M][K] @ B[N][K]^T (+ bias[N])
// 128x128 block tile, BK=8, 256 threads, 8x8 per thread (2x2 sub-tiles of 4)
// ---------------------------------------------------------------------------
__global__ __launch_bounds__(256) void sgemm_nt(const float* __restrict__ A,
    const float* __restrict__ B, const float* __restrict__ bias,
    float* __restrict__ C, int M, int N, int K) {
  __shared__ float As[8][132];
  __shared__ float Bs[8][132];
  int bm = blockIdx.y * 128, bn = blockIdx.x * 128;
  int tid = threadIdx.x;
  int tm4 = (tid >> 4) * 4;     // 0..60
  int tn4 = (tid & 15) * 4;     // 0..60
  float acc[8][8];
  #pragma unroll
  for (int i = 0; i < 8; i++)
    #pragma unroll
    for (int j = 0; j < 8; j++) acc[i][j] = 0.f;

  for (int k0 = 0; k0 < K; k0 += 8) {
    int r = tid >> 1;             // 0..127
    int kq = (tid & 1) * 4;       // 0 or 4
    int gm = bm + r, gn = bn + r;
    #pragma unroll
    for (int j = 0; j < 4; j++) {
      int gk = k0 + kq + j;
      As[kq + j][r] = (gm < M && gk < K) ? A[(size_t)gm * K + gk] : 0.f;
      Bs[kq + j][r] = (gn < N && gk < K) ? B[(size_t)gn * K + gk] : 0.f;
    }
    __syncthreads();
    #pragma unroll
    for (int kk = 0; kk < 8; kk++) {
      float a[8], b[8];
      #pragma unroll
      for (int i = 0; i < 4; i++) { a[i] = As[kk][tm4 + i]; a[i + 4] = As[kk][64 + tm4 + i]; }
      #pragma unroll
      for (int j = 0; j < 4; j++) { b[j] = Bs[kk][tn4 + j]; b[j + 4] = Bs[kk][64 + tn4 + j]; }
      #pragma unroll
      for (int i = 0; i < 8; i++)
        #pragma unroll
        for (int j = 0; j < 8; j++) acc[i][j] += a[i] * b[j];
    }
    __syncthreads();
  }
  #pragma unroll
  for (int i = 0; i < 8; i++) {
    int gm = bm + ((i < 4) ? (tm4 + i) : (64 + tm4 + i - 4));
    if (gm >= M) continue;
    #pragma unroll
    for (int j = 0; j < 8; j++) {
      int gn = bn + ((j < 4) ? (tn4 + j) : (64 + tn4 + j - 4));
      if (gn < N) C[(size_t)gm * N + gn] = acc[i][j] + (bias ? bias[gn] : 0.f);
    }
  }
}

// ---------------------------------------------------------------------------
// Prep: Wall = [WxF; WxB] (192x128), ball = [bxF; bxB], WhT[k][g] = lstm_Wh[g][k]
// ---------------------------------------------------------------------------
__global__ __launch_bounds__(256) void k_prep(const float* __restrict__ WxF,
    const float* __restrict__ WxB, const float* __restrict__ bxF,
    const float* __restrict__ bxB, const float* __restrict__ lstm_Wh,
    float* __restrict__ Wall, float* __restrict__ ball, float* __restrict__ WhT) {
  int i = blockIdx.x * 256 + threadIdx.x;
  if (i < 96 * 128) Wall[i] = WxF[i];
  else if (i < 192 * 128) Wall[i] = WxB[i - 96 * 128];
  if (i < 512 * 128) { int g = i >> 7, k = i & 127; WhT[k * 512 + g] = lstm_Wh[i]; }
  if (i < 96) ball[i] = bxF[i];
  else if (i < 192) ball[i] = bxB[i - 96];
}

// ---------------------------------------------------------------------------
// Tree: per tree gather 15 rows of E' (pre-projected emb), bottom-up subtree
// sums, max over nodes with bias*subtree_count folded in. 2 trees per block.
// ---------------------------------------------------------------------------
__global__ __launch_bounds__(256) void k_tree(const int* __restrict__ ast,
    const float* __restrict__ Ep, const float* __restrict__ Wc_b,
    float* __restrict__ x) {
  int lt = threadIdx.x >> 7;      // 0/1
  int d  = threadIdx.x & 127;
  int tree = blockIdx.x * 2 + lt;
  __shared__ int toks[2][15];
  if (d < 15) toks[lt][d] = ast[(size_t)tree * 15 + d];
  __syncthreads();
  float e[15];
  #pragma unroll
  for (int n = 0; n < 15; n++) e[n] = Ep[(size_t)toks[lt][n] * 128 + d];
  float b = Wc_b[d];
  float s3 = e[3] + e[7] + e[8],  s4 = e[4] + e[9] + e[10];
  float s5 = e[5] + e[11] + e[12], s6 = e[6] + e[13] + e[14];
  float s1 = e[1] + s3 + s4, s2 = e[2] + s5 + s6;
  float s0 = e[0] + s1 + s2;
  float ml = fmaxf(fmaxf(fmaxf(e[7], e[8]), fmaxf(e[9], e[10])),
                   fmaxf(fmaxf(e[11], e[12]), fmaxf(e[13], e[14]))) + b;
  float mm = fmaxf(fmaxf(s3, s4), fmaxf(s5, s6)) + 3.f * b;
  float mt = fmaxf(s1, s2) + 7.f * b;
  float m = fmaxf(fmaxf(ml, mm), fmaxf(mt, s0 + 15.f * b));
  x[(size_t)tree * 128 + d] = m;
}

// ---------------------------------------------------------------------------
// GRU recurrence, one block per (sequence, direction). Hidden=32, gates=96.
// xe_all[row][dir*96+g] precomputed (includes bx). Time-max accumulated.
// ---------------------------------------------------------------------------
__global__ __launch_bounds__(128) void k_gru(const float* __restrict__ xe_all,
    const float* __restrict__ WhF, const float* __restrict__ WhB,
    const float* __restrict__ bhF, const float* __restrict__ bhB,
    float* __restrict__ code) {
  int bsq = blockIdx.x >> 1, dir = blockIdx.x & 1;
  int g = threadIdx.x;
  __shared__ float whs[96 * 32];
  __shared__ float h_lds[32];
  __shared__ float rz[64];
  __shared__ float nn[32];
  const float* Wh = dir ? WhB : WhF;
  const float* bh = dir ? bhB : bhF;
  for (int i = g; i < 96 * 32; i += 128) whs[i] = Wh[i];
  if (g < 32) h_lds[g] = 0.f;
  __syncthreads();
  float w[32]; float bhv = 0.f, mxv = -1e30f;
  if (g < 96) {
    #pragma unroll
    for (int j = 0; j < 32; j++) w[j] = whs[g * 32 + j];
    bhv = bh[g];
  }
  for (int s = 0; s < 16; s++) {
    int t = dir ? (15 - s) : s;
    const float* xe = xe_all + ((size_t)(bsq * 16 + t)) * 192 + dir * 96;
    float gh = bhv, xv = 0.f;
    if (g < 96) {
      xv = xe[g];
      #pragma unroll
      for (int j = 0; j < 32; j++) gh += w[j] * h_lds[j];
    }
    if (g < 64) rz[g] = 1.f / (1.f + expf(-(xv + gh)));
    __syncthreads();
    if (g >= 64 && g < 96) nn[g - 64] = tanhf(xv + rz[g - 64] * gh);
    __syncthreads();
    if (g < 32) {
      float z = rz[g + 32];
      float hn = (1.f - z) * nn[g] + z * h_lds[g];
      mxv = fmaxf(mxv, hn);
      h_lds[g] = hn;
    }
    __syncthreads();
  }
  if (g < 32) code[(size_t)bsq * 64 + dir * 32 + g] = mxv;
}

// ---------------------------------------------------------------------------
// Build lin = [c_embed(101) | code(64) | cur_result(2)]
// ---------------------------------------------------------------------------
__global__ __launch_bounds__(256) void k_lin(const float* __restrict__ c_embed,
    const float* __restrict__ code, const float* __restrict__ cur,
    float* __restrict__ lin) {
  int i = blockIdx.x * 256 + threadIdx.x;
  if (i >= NROW * LIN_D) return;
  int row = i / LIN_D, j = i - row * LIN_D;
  float v;
  if (j < 101) v = c_embed[row * 101 + j];
  else if (j < 165) v = code[row * 64 + (j - 101)];
  else v = cur[row * 2 + (j - 165)];
  lin[i] = v;
}

// ---------------------------------------------------------------------------
// LSTM recurrence: one block per batch row (32 blocks x 512 threads).
// xeL includes bx. WhT is transposed (128 x 512) for coalesced reads.
// ---------------------------------------------------------------------------
__global__ __launch_bounds__(512) void k_lstm(const float* __restrict__ xeL,
    const float* __restrict__ WhT, const float* __restrict__ bh,
    float* __restrict__ lout) {
  int b = blockIdx.x; int g = threadIdx.x;
  __shared__ float h_lds[128];
  __shared__ float ga[512];
  float c = 0.f;
  float bhv = bh[g];
  if (g < 128) h_lds[g] = 0.f;
  __syncthreads();
  for (int t = 0; t < 50; t++) {
    float acc = xeL[((size_t)b * 50 + t) * 512 + g] + bhv;
    #pragma unroll 8
    for (int k = 0; k < 128; k++) acc += h_lds[k] * WhT[k * 512 + g];
    ga[g] = acc;
    __syncthreads();
    if (g < 128) {
      float iv = 1.f / (1.f + expf(-ga[g]));
      float fv = 1.f / (1.f + expf(-ga[g + 128]));
      float gv = tanhf(ga[g + 256]);
      float ov = 1.f / (1.f + expf(-ga[g + 384]));
      c = fv * c + iv * gv;
      float h = ov * tanhf(c);
      h_lds[g] = h;
      lout[((size_t)b * 50 + t) * 128 + g] = h;
    }
    __syncthreads();
  }
}

// ---------------------------------------------------------------------------
// Prediction head: p1 = lout . (pred_w^T tc) + tc . pred_b ; fp, masks,
// out[1+row] = sigmoid(fp)*m, out[1601+row] = result*m.
// ---------------------------------------------------------------------------
__global__ __launch_bounds__(128) void k_pred(const float* __restrict__ lout,
    const float* __restrict__ pred_w, const float* __restrict__ pred_b,
    const float* __restrict__ tc, const float* __restrict__ result,
    float* __restrict__ out, float* __restrict__ fpbuf, float* __restrict__ mbuf) {
  int row = blockIdx.x; int k = threadIdx.x;
  __shared__ float tcs[101];
  __shared__ float r1[128], r2[128], r3[128];
  if (k < 101) tcs[k] = tc[(size_t)row * 101 + k];
  __syncthreads();
  float lk = lout[(size_t)row * 128 + k];
  float acc = 0.f;
  for (int c = 0; c < 101; c++) acc += tcs[c] * pred_w[c * 128 + k];
  float v = acc * lk;
  float pb = (k < 101) ? tcs[k] * pred_b[k] : 0.f;
  float nc = (k < 101) ? tcs[k] : 0.f;
  r1[k] = v; r2[k] = pb; r3[k] = nc;
  __syncthreads();
  for (int st = 64; st > 0; st >>= 1) {
    if (k < st) { r1[k] += r1[k + st]; r2[k] += r2[k + st]; r3[k] += r3[k + st]; }
    __syncthreads();
  }
  if (k == 0) {
    float ncon = r3[0];
    float m = (ncon > 0.f) ? 1.f : 0.f;
    float fp = (r1[0] + r2[0]) / fmaxf(ncon, 1.f);
    fpbuf[row] = fp; mbuf[row] = m;
    out[1 + row] = m / (1.f + expf(-fp));
    out[1 + NROW + row] = result[row] * m;
  }
}

// ---------------------------------------------------------------------------
// Loss reduction (single block, deterministic tree reduce)
// ---------------------------------------------------------------------------
__global__ __launch_bounds__(256) void k_loss(const float* __restrict__ fpbuf,
    const float* __restrict__ mbuf, const float* __restrict__ result,
    float* __restrict__ out) {
  __shared__ float sb[256], sm[256];
  int k = threadIdx.x;
  float ab = 0.f, am = 0.f;
  for (int r = k; r < NROW; r += 256) {
    float fp = fpbuf[r], m = mbuf[r], res = result[r];
    float bce = fmaxf(fp, 0.f) - fp * res + log1pf(expf(-fabsf(fp)));
    ab += bce * m; am += m;
  }
  sb[k] = ab; sm[k] = am;
  __syncthreads();
  for (int st = 128; st > 0; st >>= 1) {
    if (k < st) { sb[k] += sb[k + st]; sm[k] += sm[k + st]; }
    __syncthreads();
  }
  if (k == 0) out[0] = sb[0] / fmaxf(sm[0], 1.f);
}

// ---------------------------------------------------------------------------
extern "C" void kernel_launch(void* const* d_in, const int* in_sizes, int n_in,
                              void* d_out, int out_size, void* d_ws, size_t ws_size,
                              hipStream_t stream) {
  (void)in_sizes; (void)n_in; (void)out_size; (void)ws_size;
  const int*   ast      = (const int*)  d_in[2];
  const float* target_c = (const float*)d_in[3];
  const float* c_embed  = (const float*)d_in[4];
  const float* cur_res  = (const float*)d_in[5];
  const float* result   = (const float*)d_in[6];
  const float* emb      = (const float*)d_in[7];
  const float* Wc_w     = (const float*)d_in[8];
  const float* Wc_b     = (const float*)d_in[9];
  const float* gru_WxF  = (const float*)d_in[10];
  const float* gru_WhF  = (const float*)d_in[11];
  const float* gru_bxF  = (const float*)d_in[12];
  const float* gru_bhF  = (const float*)d_in[13];
  const float* gru_WxB  = (const float*)d_in[14];
  const float* gru_WhB  = (const float*)d_in[15];
  const float* gru_bxB  = (const float*)d_in[16];
  const float* gru_bhB  = (const float*)d_in[17];
  const float* lstm_Wx  = (const float*)d_in[18];
  const float* lstm_Wh  = (const float*)d_in[19];
  const float* lstm_bx  = (const float*)d_in[20];
  const float* lstm_bh  = (const float*)d_in[21];
  const float* pred_w   = (const float*)d_in[22];
  const float* pred_b   = (const float*)d_in[23];
  float* out = (float*)d_out;

  float* W = (float*)d_ws;
  float* Ep     = W;                 // 6,400,000 (VOCAB*128)
  float* xe_all = W;                 // alias: 25600*192 = 4,915,200 <= Ep size
  float* x      = W + 6400000;       // 3,276,800
  float* Wall   = W + 9676800;       // 24,576
  float* ball   = W + 9701376;       // 192
  float* WhT    = W + 9701568;       // 65,536
  float* code   = W + 9767104;       // 102,400
  float* lin    = W + 9869504;       // 267,200
  float* xeL    = W + 10136704;      // 819,200
  float* lout   = W + 10955904;      // 204,800
  float* fpbuf  = W + 11160704;      // 1,600
  float* mbuf   = W + 11162304;      // 1,600

  // 1. E' = emb @ Wc_w^T   (vocab-level projection: 1.64 GFLOP vs 12.6 naive)
  sgemm_nt<<<dim3(1, 391), 256, 0, stream>>>(emb, Wc_w, nullptr, Ep, VOCAB, 128, 128);
  // 2. weight prep
  k_prep<<<256, 256, 0, stream>>>(gru_WxF, gru_WxB, gru_bxF, gru_bxB, lstm_Wh,
                                  Wall, ball, WhT);
  // 3. tree gather/sum/max -> x (25600 x 128)
  k_tree<<<NTREE / 2, 256, 0, stream>>>(ast, Ep, Wc_b, x);
  // 4. xe_all = x @ Wall^T + ball  (25600 x 192)  [aliases Ep region]
  sgemm_nt<<<dim3(2, 200), 256, 0, stream>>>(x, Wall, ball, xe_all, NTREE, 192, 128);
  // 5. GRU recurrence + time max -> code (1600 x 64)
  k_gru<<<NROW * 2, 128, 0, stream>>>(xe_all, gru_WhF, gru_WhB, gru_bhF, gru_bhB, code);
  // 6. lin build (1600 x 167)
  k_lin<<<(NROW * LIN_D + 255) / 256, 256, 0, stream>>>(c_embed, code, cur_res, lin);
  // 7. xeL = lin @ lstm_Wx^T + lstm_bx (1600 x 512)
  sgemm_nt<<<dim3(4, 13), 256, 0, stream>>>(lin, lstm_Wx, lstm_bx, xeL, NROW, 512, LIN_D);
  // 8. LSTM recurrence -> lout (1600 x 128)
  k_lstm<<<BS, 512, 0, stream>>>(xeL, WhT, lstm_bh, lout);
  // 9. prediction head -> out[1..], fpbuf, mbuf
  k_pred<<<NROW, 128, 0, stream>>>(lout, pred_w, pred_b, target_c, result,
                                   out, fpbuf, mbuf);
  // 10. loss -> out[0]
  k_loss<<<1, 256, 0, stream>>>(fpbuf, mbuf, result, out);
}

// Round 2
// 342.409 us; speedup vs baseline: 1.2378x; 1.2378x over previous
//
#include <hip/hip_runtime.h>
#include <hip/hip_bf16.h>
#include <math.h>

// Problem constants
#define BS 32
#define SEQ 50
#define ML 16
#define NN 15
#define NTREE (BS*SEQ*ML)     // 25600
#define NROW (BS*SEQ)         // 1600
#define VOCAB 50000
#define EMB 128
#define ENC 128
#define GH 32
#define NC 100
#define LH 128
#define LIN_D 167             // 101 + 64 + 2

// ---------------------------------------------------------------------------
// Generic fp32 GEMM: C[M][N] = A[M][K] @ B[N][K]^T (+ bias[N])
// 128x128 block tile, BK=8, 256 threads, 8x8 per thread (2x2 sub-tiles of 4)
// ---------------------------------------------------------------------------
__global__ __launch_bounds__(256) void sgemm_nt(const float* __restrict__ A,
    const float* __restrict__ B, const float* __restrict__ bias,
    float* __restrict__ C, int M, int N, int K) {
  __shared__ float As[8][132];
  __shared__ float Bs[8][132];
  int bm = blockIdx.y * 128, bn = blockIdx.x * 128;
  int tid = threadIdx.x;
  int tm4 = (tid >> 4) * 4;     // 0..60
  int tn4 = (tid & 15) * 4;     // 0..60
  float acc[8][8];
  #pragma unroll
  for (int i = 0; i < 8; i++)
    #pragma unroll
    for (int j = 0; j < 8; j++) acc[i][j] = 0.f;

  for (int k0 = 0; k0 < K; k0 += 8) {
    int r = tid >> 1;             // 0..127
    int kq = (tid & 1) * 4;       // 0 or 4
    int gm = bm + r, gn = bn + r;
    #pragma unroll
    for (int j = 0; j < 4; j++) {
      int gk = k0 + kq + j;
      As[kq + j][r] = (gm < M && gk < K) ? A[(size_t)gm * K + gk] : 0.f;
      Bs[kq + j][r] = (gn < N && gk < K) ? B[(size_t)gn * K + gk] : 0.f;
    }
    __syncthreads();
    #pragma unroll
    for (int kk = 0; kk < 8; kk++) {
      float a[8], b[8];
      #pragma unroll
      for (int i = 0; i < 4; i++) { a[i] = As[kk][tm4 + i]; a[i + 4] = As[kk][64 + tm4 + i]; }
      #pragma unroll
      for (int j = 0; j < 4; j++) { b[j] = Bs[kk][tn4 + j]; b[j + 4] = Bs[kk][64 + tn4 + j]; }
      #pragma unroll
      for (int i = 0; i < 8; i++)
        #pragma unroll
        for (int j = 0; j < 8; j++) acc[i][j] += a[i] * b[j];
    }
    __syncthreads();
  }
  #pragma unroll
  for (int i = 0; i < 8; i++) {
    int gm = bm + ((i < 4) ? (tm4 + i) : (64 + tm4 + i - 4));
    if (gm >= M) continue;
    #pragma unroll
    for (int j = 0; j < 8; j++) {
      int gn = bn + ((j < 4) ? (tn4 + j) : (64 + tn4 + j - 4));
      if (gn < N) C[(size_t)gm * N + gn] = acc[i][j] + (bias ? bias[gn] : 0.f);
    }
  }
}

// ---------------------------------------------------------------------------
// Prep: Wall = [WxF; WxB] (192x128), ball = [bxF; bxB]
// ---------------------------------------------------------------------------
__global__ __launch_bounds__(256) void k_prep(const float* __restrict__ WxF,
    const float* __restrict__ WxB, const float* __restrict__ bxF,
    const float* __restrict__ bxB,
    float* __restrict__ Wall, float* __restrict__ ball) {
  int i = blockIdx.x * 256 + threadIdx.x;
  if (i < 96 * 128) Wall[i] = WxF[i];
  else if (i < 192 * 128) Wall[i] = WxB[i - 96 * 128];
  if (i < 96) ball[i] = bxF[i];
  else if (i < 192) ball[i] = bxB[i - 96];
}

// ---------------------------------------------------------------------------
// Tree: per tree gather 15 rows of E' (pre-projected emb), bottom-up subtree
// sums, max over nodes with bias*subtree_count folded in. 2 trees per block.
// ---------------------------------------------------------------------------
__global__ __launch_bounds__(256) void k_tree(const int* __restrict__ ast,
    const float* __restrict__ Ep, const float* __restrict__ Wc_b,
    float* __restrict__ x) {
  int lt = threadIdx.x >> 7;      // 0/1
  int d  = threadIdx.x & 127;
  int tree = blockIdx.x * 2 + lt;
  __shared__ int toks[2][15];
  if (d < 15) toks[lt][d] = ast[(size_t)tree * 15 + d];
  __syncthreads();
  float e[15];
  #pragma unroll
  for (int n = 0; n < 15; n++) e[n] = Ep[(size_t)toks[lt][n] * 128 + d];
  float b = Wc_b[d];
  float s3 = e[3] + e[7] + e[8],  s4 = e[4] + e[9] + e[10];
  float s5 = e[5] + e[11] + e[12], s6 = e[6] + e[13] + e[14];
  float s1 = e[1] + s3 + s4, s2 = e[2] + s5 + s6;
  float s0 = e[0] + s1 + s2;
  float ml = fmaxf(fmaxf(fmaxf(e[7], e[8]), fmaxf(e[9], e[10])),
                   fmaxf(fmaxf(e[11], e[12]), fmaxf(e[13], e[14]))) + b;
  float mm = fmaxf(fmaxf(s3, s4), fmaxf(s5, s6)) + 3.f * b;
  float mt = fmaxf(s1, s2) + 7.f * b;
  float m = fmaxf(fmaxf(ml, mm), fmaxf(mt, s0 + 15.f * b));
  x[(size_t)tree * 128 + d] = m;
}

// ---------------------------------------------------------------------------
// GRU recurrence, one block per (sequence, direction). Hidden=32, gates=96.
// xe_all[row][dir*96+g] precomputed (includes bx). Time-max accumulated.
// ---------------------------------------------------------------------------
__global__ __launch_bounds__(128) void k_gru(const float* __restrict__ xe_all,
    const float* __restrict__ WhF, const float* __restrict__ WhB,
    const float* __restrict__ bhF, const float* __restrict__ bhB,
    float* __restrict__ code) {
  int bsq = blockIdx.x >> 1, dir = blockIdx.x & 1;
  int g = threadIdx.x;
  __shared__ float whs[96 * 32];
  __shared__ float h_lds[32];
  __shared__ float rz[64];
  __shared__ float nn[32];
  const float* Wh = dir ? WhB : WhF;
  const float* bh = dir ? bhB : bhF;
  for (int i = g; i < 96 * 32; i += 128) whs[i] = Wh[i];
  if (g < 32) h_lds[g] = 0.f;
  __syncthreads();
  float w[32]; float bhv = 0.f, mxv = -1e30f;
  if (g < 96) {
    #pragma unroll
    for (int j = 0; j < 32; j++) w[j] = whs[g * 32 + j];
    bhv = bh[g];
  }
  for (int s = 0; s < 16; s++) {
    int t = dir ? (15 - s) : s;
    const float* xe = xe_all + ((size_t)(bsq * 16 + t)) * 192 + dir * 96;
    float gh = bhv, xv = 0.f;
    if (g < 96) {
      xv = xe[g];
      #pragma unroll
      for (int j = 0; j < 32; j++) gh += w[j] * h_lds[j];
    }
    if (g < 64) rz[g] = 1.f / (1.f + expf(-(xv + gh)));
    __syncthreads();
    if (g >= 64 && g < 96) nn[g - 64] = tanhf(xv + rz[g - 64] * gh);
    __syncthreads();
    if (g < 32) {
      float z = rz[g + 32];
      float hn = (1.f - z) * nn[g] + z * h_lds[g];
      mxv = fmaxf(mxv, hn);
      h_lds[g] = hn;
    }
    __syncthreads();
  }
  if (g < 32) code[(size_t)bsq * 64 + dir * 32 + g] = mxv;
}

// ---------------------------------------------------------------------------
// Build lin = [c_embed(101) | code(64) | cur_result(2)]
// ---------------------------------------------------------------------------
__global__ __launch_bounds__(256) void k_lin(const float* __restrict__ c_embed,
    const float* __restrict__ code, const float* __restrict__ cur,
    float* __restrict__ lin) {
  int i = blockIdx.x * 256 + threadIdx.x;
  if (i >= NROW * LIN_D) return;
  int row = i / LIN_D, j = i - row * LIN_D;
  float v;
  if (j < 101) v = c_embed[row * 101 + j];
  else if (j < 165) v = code[row * 64 + (j - 101)];
  else v = cur[row * 2 + (j - 165)];
  lin[i] = v;
}

// ---------------------------------------------------------------------------
// LSTM recurrence: one block per batch row (32 blocks x 512 threads).
// Thread g owns gate g; its weight row Wh[g][0..127] lives in 32 float4
// REGISTERS (loaded once). Per step: 32 broadcast ds_read_b128 of h + 128
// register FMAs. xeL includes bx.
// ---------------------------------------------------------------------------
__global__ __launch_bounds__(512, 2) void k_lstm(const float* __restrict__ xeL,
    const float* __restrict__ Wh, const float* __restrict__ bh,
    float* __restrict__ lout) {
  int b = blockIdx.x; int g = threadIdx.x;
  __shared__ float h_lds[128];
  __shared__ float ga[512];
  float4 w[32];
  const float4* wsrc = (const float4*)(Wh + (size_t)g * 128);
  #pragma unroll
  for (int i = 0; i < 32; i++) w[i] = wsrc[i];
  float bhv = bh[g];
  float c = 0.f;
  if (g < 128) h_lds[g] = 0.f;
  __syncthreads();
  for (int t = 0; t < 50; t++) {
    float acc = xeL[((size_t)b * 50 + t) * 512 + g] + bhv;
    const float4* hv = (const float4*)h_lds;
    #pragma unroll
    for (int i = 0; i < 32; i++) {
      float4 h4 = hv[i];
      acc += h4.x * w[i].x + h4.y * w[i].y + h4.z * w[i].z + h4.w * w[i].w;
    }
    ga[g] = acc;
    __syncthreads();
    if (g < 128) {
      float iv = 1.f / (1.f + expf(-ga[g]));
      float fv = 1.f / (1.f + expf(-ga[g + 128]));
      float gv = tanhf(ga[g + 256]);
      float ov = 1.f / (1.f + expf(-ga[g + 384]));
      c = fv * c + iv * gv;
      float h = ov * tanhf(c);
      h_lds[g] = h;
      lout[((size_t)b * 50 + t) * 128 + g] = h;
    }
    __syncthreads();
  }
}

// ---------------------------------------------------------------------------
// Prediction head: p1 = lout . (pred_w^T tc) + tc . pred_b ; fp, masks,
// out[1+row] = sigmoid(fp)*m, out[1601+row] = result*m.
// ---------------------------------------------------------------------------
__global__ __launch_bounds__(128) void k_pred(const float* __restrict__ lout,
    const float* __restrict__ pred_w, const float* __restrict__ pred_b,
    const float* __restrict__ tc, const float* __restrict__ result,
    float* __restrict__ out, float* __restrict__ fpbuf, float* __restrict__ mbuf) {
  int row = blockIdx.x; int k = threadIdx.x;
  __shared__ float tcs[101];
  __shared__ float r1[128], r2[128], r3[128];
  if (k < 101) tcs[k] = tc[(size_t)row * 101 + k];
  __syncthreads();
  float lk = lout[(size_t)row * 128 + k];
  float acc = 0.f;
  for (int c = 0; c < 101; c++) acc += tcs[c] * pred_w[c * 128 + k];
  float v = acc * lk;
  float pb = (k < 101) ? tcs[k] * pred_b[k] : 0.f;
  float nc = (k < 101) ? tcs[k] : 0.f;
  r1[k] = v; r2[k] = pb; r3[k] = nc;
  __syncthreads();
  for (int st = 64; st > 0; st >>= 1) {
    if (k < st) { r1[k] += r1[k + st]; r2[k] += r2[k + st]; r3[k] += r3[k + st]; }
    __syncthreads();
  }
  if (k == 0) {
    float ncon = r3[0];
    float m = (ncon > 0.f) ? 1.f : 0.f;
    float fp = (r1[0] + r2[0]) / fmaxf(ncon, 1.f);
    fpbuf[row] = fp; mbuf[row] = m;
    out[1 + row] = m / (1.f + expf(-fp));
    out[1 + NROW + row] = result[row] * m;
  }
}

// ---------------------------------------------------------------------------
// Loss reduction (single block, deterministic tree reduce)
// ---------------------------------------------------------------------------
__global__ __launch_bounds__(256) void k_loss(const float* __restrict__ fpbuf,
    const float* __restrict__ mbuf, const float* __restrict__ result,
    float* __restrict__ out) {
  __shared__ float sb[256], sm[256];
  int k = threadIdx.x;
  float ab = 0.f, am = 0.f;
  for (int r = k; r < NROW; r += 256) {
    float fp = fpbuf[r], m = mbuf[r], res = result[r];
    float bce = fmaxf(fp, 0.f) - fp * res + log1pf(expf(-fabsf(fp)));
    ab += bce * m; am += m;
  }
  sb[k] = ab; sm[k] = am;
  __syncthreads();
  for (int st = 128; st > 0; st >>= 1) {
    if (k < st) { sb[k] += sb[k + st]; sm[k] += sm[k + st]; }
    __syncthreads();
  }
  if (k == 0) out[0] = sb[0] / fmaxf(sm[0], 1.f);
}

// ---------------------------------------------------------------------------
extern "C" void kernel_launch(void* const* d_in, const int* in_sizes, int n_in,
                              void* d_out, int out_size, void* d_ws, size_t ws_size,
                              hipStream_t stream) {
  (void)in_sizes; (void)n_in; (void)out_size; (void)ws_size;
  const int*   ast      = (const int*)  d_in[2];
  const float* target_c = (const float*)d_in[3];
  const float* c_embed  = (const float*)d_in[4];
  const float* cur_res  = (const float*)d_in[5];
  const float* result   = (const float*)d_in[6];
  const float* emb      = (const float*)d_in[7];
  const float* Wc_w     = (const float*)d_in[8];
  const float* Wc_b     = (const float*)d_in[9];
  const float* gru_WxF  = (const float*)d_in[10];
  const float* gru_WhF  = (const float*)d_in[11];
  const float* gru_bxF  = (const float*)d_in[12];
  const float* gru_bhF  = (const float*)d_in[13];
  const float* gru_WxB  = (const float*)d_in[14];
  const float* gru_WhB  = (const float*)d_in[15];
  const float* gru_bxB  = (const float*)d_in[16];
  const float* gru_bhB  = (const float*)d_in[17];
  const float* lstm_Wx  = (const float*)d_in[18];
  const float* lstm_Wh  = (const float*)d_in[19];
  const float* lstm_bx  = (const float*)d_in[20];
  const float* lstm_bh  = (const float*)d_in[21];
  const float* pred_w   = (const float*)d_in[22];
  const float* pred_b   = (const float*)d_in[23];
  float* out = (float*)d_out;

  float* W = (float*)d_ws;
  float* Ep     = W;                 // 6,400,000 (VOCAB*128)
  float* xe_all = W;                 // alias: 25600*192 = 4,915,200 <= Ep size
  float* x      = W + 6400000;       // 3,276,800
  float* Wall   = W + 9676800;       // 24,576
  float* ball   = W + 9701376;       // 192
  float* code   = W + 9767104;       // 102,400
  float* lin    = W + 9869504;       // 267,200
  float* xeL    = W + 10136704;      // 819,200
  float* lout   = W + 10955904;      // 204,800
  float* fpbuf  = W + 11160704;      // 1,600
  float* mbuf   = W + 11162304;      // 1,600

  // 1. E' = emb @ Wc_w^T   (vocab-level projection: 1.64 GFLOP vs 12.6 naive)
  sgemm_nt<<<dim3(1, 391), 256, 0, stream>>>(emb, Wc_w, nullptr, Ep, VOCAB, 128, 128);
  // 2. weight prep
  k_prep<<<256, 256, 0, stream>>>(gru_WxF, gru_WxB, gru_bxF, gru_bxB, Wall, ball);
  // 3. tree gather/sum/max -> x (25600 x 128)
  k_tree<<<NTREE / 2, 256, 0, stream>>>(ast, Ep, Wc_b, x);
  // 4. xe_all = x @ Wall^T + ball  (25600 x 192)  [aliases Ep region]
  sgemm_nt<<<dim3(2, 200), 256, 0, stream>>>(x, Wall, ball, xe_all, NTREE, 192, 128);
  // 5. GRU recurrence + time max -> code (1600 x 64)
  k_gru<<<NROW * 2, 128, 0, stream>>>(xe_all, gru_WhF, gru_WhB, gru_bhF, gru_bhB, code);
  // 6. lin build (1600 x 167)
  k_lin<<<(NROW * LIN_D + 255) / 256, 256, 0, stream>>>(c_embed, code, cur_res, lin);
  // 7. xeL = lin @ lstm_Wx^T + lstm_bx (1600 x 512)
  sgemm_nt<<<dim3(4, 13), 256, 0, stream>>>(lin, lstm_Wx, lstm_bx, xeL, NROW, 512, LIN_D);
  // 8. LSTM recurrence -> lout (1600 x 128)  [weights in registers]
  k_lstm<<<BS, 512, 0, stream>>>(xeL, lstm_Wh, lstm_bh, lout);
  // 9. prediction head -> out[1..], fpbuf, mbuf
  k_pred<<<NROW, 128, 0, stream>>>(lout, pred_w, pred_b, target_c, result,
                                   out, fpbuf, mbuf);
  // 10. loss -> out[0]
  k_loss<<<1, 256, 0, stream>>>(fpbuf, mbuf, result, out);
}

// Round 3
// 340.513 us; speedup vs baseline: 1.2447x; 1.0056x over previous
//
#include <hip/hip_runtime.h>
#include <hip/hip_bf16.h>
#include <math.h>

// Problem constants
#define BS 32
#define SEQ 50
#define ML 16
#define NN 15
#define NTREE (BS*SEQ*ML)     // 25600
#define NROW (BS*SEQ)         // 1600
#define VOCAB 50000
#define EMB 128
#define ENC 128
#define GH 32
#define NC 100
#define LH 128
#define LIN_D 167             // 101 + 64 + 2

// ---------------------------------------------------------------------------
// Generic fp32 GEMM: C[M][N] = A[M][K] @ B[N][K]^T (+ bias[N])
// 128x128 block tile, BK=8, 256 threads, 8x8 per thread.
// LDS reads vectorized as float4 (row stride 132 floats = 528 B, 16B-aligned).
// ---------------------------------------------------------------------------
__global__ __launch_bounds__(256) void sgemm_nt(const float* __restrict__ A,
    const float* __restrict__ B, const float* __restrict__ bias,
    float* __restrict__ C, int M, int N, int K) {
  __shared__ float As[8][132];
  __shared__ float Bs[8][132];
  int bm = blockIdx.y * 128, bn = blockIdx.x * 128;
  int tid = threadIdx.x;
  int tm4 = (tid >> 4) * 4;     // 0..60
  int tn4 = (tid & 15) * 4;     // 0..60
  float acc[8][8];
  #pragma unroll
  for (int i = 0; i < 8; i++)
    #pragma unroll
    for (int j = 0; j < 8; j++) acc[i][j] = 0.f;

  for (int k0 = 0; k0 < K; k0 += 8) {
    int r = tid >> 1;             // 0..127
    int kq = (tid & 1) * 4;       // 0 or 4
    int gm = bm + r, gn = bn + r;
    #pragma unroll
    for (int j = 0; j < 4; j++) {
      int gk = k0 + kq + j;
      As[kq + j][r] = (gm < M && gk < K) ? A[(size_t)gm * K + gk] : 0.f;
      Bs[kq + j][r] = (gn < N && gk < K) ? B[(size_t)gn * K + gk] : 0.f;
    }
    __syncthreads();
    #pragma unroll
    for (int kk = 0; kk < 8; kk++) {
      float4 a0 = *(const float4*)&As[kk][tm4];
      float4 a1 = *(const float4*)&As[kk][64 + tm4];
      float4 b0 = *(const float4*)&Bs[kk][tn4];
      float4 b1 = *(const float4*)&Bs[kk][64 + tn4];
      float a[8] = {a0.x, a0.y, a0.z, a0.w, a1.x, a1.y, a1.z, a1.w};
      float b[8] = {b0.x, b0.y, b0.z, b0.w, b1.x, b1.y, b1.z, b1.w};
      #pragma unroll
      for (int i = 0; i < 8; i++)
        #pragma unroll
        for (int j = 0; j < 8; j++) acc[i][j] += a[i] * b[j];
    }
    __syncthreads();
  }
  #pragma unroll
  for (int i = 0; i < 8; i++) {
    int gm = bm + ((i < 4) ? (tm4 + i) : (64 + tm4 + i - 4));
    if (gm >= M) continue;
    #pragma unroll
    for (int j = 0; j < 8; j++) {
      int gn = bn + ((j < 4) ? (tn4 + j) : (64 + tn4 + j - 4));
      if (gn < N) C[(size_t)gm * N + gn] = acc[i][j] + (bias ? bias[gn] : 0.f);
    }
  }
}

// ---------------------------------------------------------------------------
// Prep: Wall = [WxF; WxB] (192x128), ball = [bxF; bxB]
// ---------------------------------------------------------------------------
__global__ __launch_bounds__(256) void k_prep(const float* __restrict__ WxF,
    const float* __restrict__ WxB, const float* __restrict__ bxF,
    const float* __restrict__ bxB,
    float* __restrict__ Wall, float* __restrict__ ball) {
  int i = blockIdx.x * 256 + threadIdx.x;
  if (i < 96 * 128) Wall[i] = WxF[i];
  else if (i < 192 * 128) Wall[i] = WxB[i - 96 * 128];
  if (i < 96) ball[i] = bxF[i];
  else if (i < 192) ball[i] = bxB[i - 96];
}

// ---------------------------------------------------------------------------
// Tree: per tree gather 15 rows of E' (pre-projected emb), bottom-up subtree
// sums, max over nodes with bias*subtree_count folded in. 2 trees per block.
// ---------------------------------------------------------------------------
__global__ __launch_bounds__(256) void k_tree(const int* __restrict__ ast,
    const float* __restrict__ Ep, const float* __restrict__ Wc_b,
    float* __restrict__ x) {
  int lt = threadIdx.x >> 7;      // 0/1
  int d  = threadIdx.x & 127;
  int tree = blockIdx.x * 2 + lt;
  __shared__ int toks[2][15];
  if (d < 15) toks[lt][d] = ast[(size_t)tree * 15 + d];
  __syncthreads();
  float e[15];
  #pragma unroll
  for (int n = 0; n < 15; n++) e[n] = Ep[(size_t)toks[lt][n] * 128 + d];
  float b = Wc_b[d];
  float s3 = e[3] + e[7] + e[8],  s4 = e[4] + e[9] + e[10];
  float s5 = e[5] + e[11] + e[12], s6 = e[6] + e[13] + e[14];
  float s1 = e[1] + s3 + s4, s2 = e[2] + s5 + s6;
  float s0 = e[0] + s1 + s2;
  float ml = fmaxf(fmaxf(fmaxf(e[7], e[8]), fmaxf(e[9], e[10])),
                   fmaxf(fmaxf(e[11], e[12]), fmaxf(e[13], e[14]))) + b;
  float mm = fmaxf(fmaxf(s3, s4), fmaxf(s5, s6)) + 3.f * b;
  float mt = fmaxf(s1, s2) + 7.f * b;
  float m = fmaxf(fmaxf(ml, mm), fmaxf(mt, s0 + 15.f * b));
  x[(size_t)tree * 128 + d] = m;
}

// ---------------------------------------------------------------------------
// GRU recurrence, one block per (sequence, direction). Hidden=32, gates=96.
// ---------------------------------------------------------------------------
__global__ __launch_bounds__(128) void k_gru(const float* __restrict__ xe_all,
    const float* __restrict__ WhF, const float* __restrict__ WhB,
    const float* __restrict__ bhF, const float* __restrict__ bhB,
    float* __restrict__ code) {
  int bsq = blockIdx.x >> 1, dir = blockIdx.x & 1;
  int g = threadIdx.x;
  __shared__ float whs[96 * 32];
  __shared__ float h_lds[32];
  __shared__ float rz[64];
  __shared__ float nn[32];
  const float* Wh = dir ? WhB : WhF;
  const float* bh = dir ? bhB : bhF;
  for (int i = g; i < 96 * 32; i += 128) whs[i] = Wh[i];
  if (g < 32) h_lds[g] = 0.f;
  __syncthreads();
  float w[32]; float bhv = 0.f, mxv = -1e30f;
  if (g < 96) {
    #pragma unroll
    for (int j = 0; j < 32; j++) w[j] = whs[g * 32 + j];
    bhv = bh[g];
  }
  for (int s = 0; s < 16; s++) {
    int t = dir ? (15 - s) : s;
    const float* xe = xe_all + ((size_t)(bsq * 16 + t)) * 192 + dir * 96;
    float gh = bhv, xv = 0.f;
    if (g < 96) {
      xv = xe[g];
      #pragma unroll
      for (int j = 0; j < 32; j++) gh += w[j] * h_lds[j];
    }
    if (g < 64) rz[g] = 1.f / (1.f + expf(-(xv + gh)));
    __syncthreads();
    if (g >= 64 && g < 96) nn[g - 64] = tanhf(xv + rz[g - 64] * gh);
    __syncthreads();
    if (g < 32) {
      float z = rz[g + 32];
      float hn = (1.f - z) * nn[g] + z * h_lds[g];
      mxv = fmaxf(mxv, hn);
      h_lds[g] = hn;
    }
    __syncthreads();
  }
  if (g < 32) code[(size_t)bsq * 64 + dir * 32 + g] = mxv;
}

// ---------------------------------------------------------------------------
// Build lin = [c_embed(101) | code(64) | cur_result(2)]
// ---------------------------------------------------------------------------
__global__ __launch_bounds__(256) void k_lin(const float* __restrict__ c_embed,
    const float* __restrict__ code, const float* __restrict__ cur,
    float* __restrict__ lin) {
  int i = blockIdx.x * 256 + threadIdx.x;
  if (i >= NROW * LIN_D) return;
  int row = i / LIN_D, j = i - row * LIN_D;
  float v;
  if (j < 101) v = c_embed[row * 101 + j];
  else if (j < 165) v = code[row * 64 + (j - 101)];
  else v = cur[row * 2 + (j - 165)];
  lin[i] = v;
}

// ---------------------------------------------------------------------------
// LSTM recurrence v3: one block per batch row, 256 threads (4 waves,
// 1 wave/SIMD, 512-VGPR budget). Thread t owns gates (t, t+256); both
// weight rows live in 64 float4 registers. h broadcast via v_readlane
// (2 ds_read_b32 per wave per step instead of 256 ds_read_b128 per block).
// Gates: t<128 -> (i_t, g_t); t>=128 -> (f_{t-128}, o_{t-128}).
// ---------------------------------------------------------------------------
#define RL(v, l) __int_as_float(__builtin_amdgcn_readlane(__float_as_int(v), (l)))

__global__ __launch_bounds__(256, 1) void k_lstm(const float* __restrict__ xeL,
    const float* __restrict__ Wh, const float* __restrict__ bh,
    float* __restrict__ lout) {
  int b = blockIdx.x; int t = threadIdx.x;
  int lane = t & 63;
  int u = t & 127;                 // unit index for this thread's gates
  __shared__ float hbuf[2][128];
  __shared__ float fo_f[128], fo_o[128];
  // load both weight rows into registers (64 float4 = 256 VGPR)
  float4 w0[32], w1[32];
  const float4* ws0 = (const float4*)(Wh + (size_t)t * 128);
  const float4* ws1 = (const float4*)(Wh + (size_t)(t + 256) * 128);
  #pragma unroll
  for (int i = 0; i < 32; i++) { w0[i] = ws0[i]; w1[i] = ws1[i]; }
  float b0 = bh[t], b1 = bh[t + 256];
  float c = 0.f;
  if (t < 128) { hbuf[0][t] = 0.f; hbuf[1][t] = 0.f; }
  const float* xrow = xeL + (size_t)b * 50 * 512;
  float xe0 = xrow[t], xe1 = xrow[t + 256];   // t=0 prefetch
  __syncthreads();
  int p = 0;
  for (int step = 0; step < 50; step++) {
    // h into this wave's lanes: lane l holds h[l] and h[64+l]
    float h0 = hbuf[p][lane];
    float h1 = hbuf[p][64 + lane];
    float acc0a = xe0 + b0, acc1a = xe1 + b1;
    float acc0b = 0.f, acc1b = 0.f;
    // prefetch next step's xe (overlaps with the dot below)
    if (step < 49) {
      const float* xn = xrow + (size_t)(step + 1) * 512;
      xe0 = xn[t]; xe1 = xn[t + 256];
    }
    #pragma unroll
    for (int i = 0; i < 16; i++) {
      float4 a = w0[i], bb = w1[i];
      float hk;
      hk = RL(h0, 4*i+0); acc0a += hk * a.x; acc1a += hk * bb.x;
      hk = RL(h0, 4*i+1); acc0b += hk * a.y; acc1b += hk * bb.y;
      hk = RL(h0, 4*i+2); acc0a += hk * a.z; acc1a += hk * bb.z;
      hk = RL(h0, 4*i+3); acc0b += hk * a.w; acc1b += hk * bb.w;
    }
    #pragma unroll
    for (int i = 0; i < 16; i++) {
      float4 a = w0[16 + i], bb = w1[16 + i];
      float hk;
      hk = RL(h1, 4*i+0); acc0a += hk * a.x; acc1a += hk * bb.x;
      hk = RL(h1, 4*i+1); acc0b += hk * a.y; acc1b += hk * bb.y;
      hk = RL(h1, 4*i+2); acc0a += hk * a.z; acc1a += hk * bb.z;
      hk = RL(h1, 4*i+3); acc0b += hk * a.w; acc1b += hk * bb.w;
    }
    float acc0 = acc0a + acc0b, acc1 = acc1a + acc1b;
    if (t >= 128) { fo_f[u] = acc0; fo_o[u] = acc1; }
    __syncthreads();
    if (t < 128) {
      float iv = 1.f / (1.f + expf(-acc0));
      float gv = tanhf(acc1);
      float fv = 1.f / (1.f + expf(-fo_f[u]));
      float ov = 1.f / (1.f + expf(-fo_o[u]));
      c = fv * c + iv * gv;
      float h = ov * tanhf(c);
      hbuf[p ^ 1][u] = h;
      lout[((size_t)b * 50 + step) * 128 + u] = h;
    }
    __syncthreads();
    p ^= 1;
  }
}

// ---------------------------------------------------------------------------
// Prediction head: p1 = lout . (pred_w^T tc) + tc . pred_b
// ---------------------------------------------------------------------------
__global__ __launch_bounds__(128) void k_pred(const float* __restrict__ lout,
    const float* __restrict__ pred_w, const float* __restrict__ pred_b,
    const float* __restrict__ tc, const float* __restrict__ result,
    float* __restrict__ out, float* __restrict__ fpbuf, float* __restrict__ mbuf) {
  int row = blockIdx.x; int k = threadIdx.x;
  __shared__ float tcs[101];
  __shared__ float r1[128], r2[128], r3[128];
  if (k < 101) tcs[k] = tc[(size_t)row * 101 + k];
  __syncthreads();
  float lk = lout[(size_t)row * 128 + k];
  float acc = 0.f;
  for (int c = 0; c < 101; c++) acc += tcs[c] * pred_w[c * 128 + k];
  float v = acc * lk;
  float pb = (k < 101) ? tcs[k] * pred_b[k] : 0.f;
  float nc = (k < 101) ? tcs[k] : 0.f;
  r1[k] = v; r2[k] = pb; r3[k] = nc;
  __syncthreads();
  for (int st = 64; st > 0; st >>= 1) {
    if (k < st) { r1[k] += r1[k + st]; r2[k] += r2[k + st]; r3[k] += r3[k + st]; }
    __syncthreads();
  }
  if (k == 0) {
    float ncon = r3[0];
    float m = (ncon > 0.f) ? 1.f : 0.f;
    float fp = (r1[0] + r2[0]) / fmaxf(ncon, 1.f);
    fpbuf[row] = fp; mbuf[row] = m;
    out[1 + row] = m / (1.f + expf(-fp));
    out[1 + NROW + row] = result[row] * m;
  }
}

// ---------------------------------------------------------------------------
// Loss reduction (single block, deterministic tree reduce)
// ---------------------------------------------------------------------------
__global__ __launch_bounds__(256) void k_loss(const float* __restrict__ fpbuf,
    const float* __restrict__ mbuf, const float* __restrict__ result,
    float* __restrict__ out) {
  __shared__ float sb[256], sm[256];
  int k = threadIdx.x;
  float ab = 0.f, am = 0.f;
  for (int r = k; r < NROW; r += 256) {
    float fp = fpbuf[r], m = mbuf[r], res = result[r];
    float bce = fmaxf(fp, 0.f) - fp * res + log1pf(expf(-fabsf(fp)));
    ab += bce * m; am += m;
  }
  sb[k] = ab; sm[k] = am;
  __syncthreads();
  for (int st = 128; st > 0; st >>= 1) {
    if (k < st) { sb[k] += sb[k + st]; sm[k] += sm[k + st]; }
    __syncthreads();
  }
  if (k == 0) out[0] = sb[0] / fmaxf(sm[0], 1.f);
}

// ---------------------------------------------------------------------------
extern "C" void kernel_launch(void* const* d_in, const int* in_sizes, int n_in,
                              void* d_out, int out_size, void* d_ws, size_t ws_size,
                              hipStream_t stream) {
  (void)in_sizes; (void)n_in; (void)out_size; (void)ws_size;
  const int*   ast      = (const int*)  d_in[2];
  const float* target_c = (const float*)d_in[3];
  const float* c_embed  = (const float*)d_in[4];
  const float* cur_res  = (const float*)d_in[5];
  const float* result   = (const float*)d_in[6];
  const float* emb      = (const float*)d_in[7];
  const float* Wc_w     = (const float*)d_in[8];
  const float* Wc_b     = (const float*)d_in[9];
  const float* gru_WxF  = (const float*)d_in[10];
  const float* gru_WhF  = (const float*)d_in[11];
  const float* gru_bxF  = (const float*)d_in[12];
  const float* gru_bhF  = (const float*)d_in[13];
  const float* gru_WxB  = (const float*)d_in[14];
  const float* gru_WhB  = (const float*)d_in[15];
  const float* gru_bxB  = (const float*)d_in[16];
  const float* gru_bhB  = (const float*)d_in[17];
  const float* lstm_Wx  = (const float*)d_in[18];
  const float* lstm_Wh  = (const float*)d_in[19];
  const float* lstm_bx  = (const float*)d_in[20];
  const float* lstm_bh  = (const float*)d_in[21];
  const float* pred_w   = (const float*)d_in[22];
  const float* pred_b   = (const float*)d_in[23];
  float* out = (float*)d_out;

  float* W = (float*)d_ws;
  float* Ep     = W;                 // 6,400,000 (VOCAB*128)
  float* xe_all = W;                 // alias: 25600*192 = 4,915,200 <= Ep size
  float* x      = W + 6400000;       // 3,276,800
  float* Wall   = W + 9676800;       // 24,576
  float* ball   = W + 9701376;       // 192
  float* code   = W + 9767104;       // 102,400
  float* lin    = W + 9869504;       // 267,200
  float* xeL    = W + 10136704;      // 819,200
  float* lout   = W + 10955904;      // 204,800
  float* fpbuf  = W + 11160704;      // 1,600
  float* mbuf   = W + 11162304;      // 1,600

  // 1. E' = emb @ Wc_w^T   (vocab-level projection)
  sgemm_nt<<<dim3(1, 391), 256, 0, stream>>>(emb, Wc_w, nullptr, Ep, VOCAB, 128, 128);
  // 2. weight prep
  k_prep<<<256, 256, 0, stream>>>(gru_WxF, gru_WxB, gru_bxF, gru_bxB, Wall, ball);
  // 3. tree gather/sum/max -> x (25600 x 128)
  k_tree<<<NTREE / 2, 256, 0, stream>>>(ast, Ep, Wc_b, x);
  // 4. xe_all = x @ Wall^T + ball  (25600 x 192)  [aliases Ep region]
  sgemm_nt<<<dim3(2, 200), 256, 0, stream>>>(x, Wall, ball, xe_all, NTREE, 192, 128);
  // 5. GRU recurrence + time max -> code (1600 x 64)
  k_gru<<<NROW * 2, 128, 0, stream>>>(xe_all, gru_WhF, gru_WhB, gru_bhF, gru_bhB, code);
  // 6. lin build (1600 x 167)
  k_lin<<<(NROW * LIN_D + 255) / 256, 256, 0, stream>>>(c_embed, code, cur_res, lin);
  // 7. xeL = lin @ lstm_Wx^T + lstm_bx (1600 x 512)
  sgemm_nt<<<dim3(4, 13), 256, 0, stream>>>(lin, lstm_Wx, lstm_bx, xeL, NROW, 512, LIN_D);
  // 8. LSTM recurrence -> lout (1600 x 128)  [readlane broadcast, 1 wave/SIMD]
  k_lstm<<<BS, 256, 0, stream>>>(xeL, lstm_Wh, lstm_bh, lout);
  // 9. prediction head -> out[1..], fpbuf, mbuf
  k_pred<<<NROW, 128, 0, stream>>>(lout, pred_w, pred_b, target_c, result,
                                   out, fpbuf, mbuf);
  // 10. loss -> out[0]
  k_loss<<<1, 256, 0, stream>>>(fpbuf, mbuf, result, out);
}

// Round 4
// 317.937 us; speedup vs baseline: 1.3330x; 1.0710x over previous
//
#include <hip/hip_runtime.h>
#include <hip/hip_bf16.h>
#include <math.h>

// Problem constants
#define BS 32
#define SEQ 50
#define ML 16
#define NN 15
#define NTREE (BS*SEQ*ML)     // 25600
#define NROW (BS*SEQ)         // 1600
#define VOCAB 50000
#define EMB 128
#define ENC 128
#define GH 32
#define NC 100
#define LH 128
#define LIN_D 167             // 101 + 64 + 2

typedef float f32x4 __attribute__((ext_vector_type(4)));

// ---------------------------------------------------------------------------
// Generic fp32 GEMM: C[M][N] = A[M][K] @ B[N][K]^T (+ bias[N])
// 128x128 block tile, BK=8, 256 threads, 8x8 per thread.
// ---------------------------------------------------------------------------
__global__ __launch_bounds__(256) void sgemm_nt(const float* __restrict__ A,
    const float* __restrict__ B, const float* __restrict__ bias,
    float* __restrict__ C, int M, int N, int K) {
  __shared__ float As[8][132];
  __shared__ float Bs[8][132];
  int bm = blockIdx.y * 128, bn = blockIdx.x * 128;
  int tid = threadIdx.x;
  int tm4 = (tid >> 4) * 4;     // 0..60
  int tn4 = (tid & 15) * 4;     // 0..60
  float acc[8][8];
  #pragma unroll
  for (int i = 0; i < 8; i++)
    #pragma unroll
    for (int j = 0; j < 8; j++) acc[i][j] = 0.f;

  for (int k0 = 0; k0 < K; k0 += 8) {
    int r = tid >> 1;             // 0..127
    int kq = (tid & 1) * 4;       // 0 or 4
    int gm = bm + r, gn = bn + r;
    #pragma unroll
    for (int j = 0; j < 4; j++) {
      int gk = k0 + kq + j;
      As[kq + j][r] = (gm < M && gk < K) ? A[(size_t)gm * K + gk] : 0.f;
      Bs[kq + j][r] = (gn < N && gk < K) ? B[(size_t)gn * K + gk] : 0.f;
    }
    __syncthreads();
    #pragma unroll
    for (int kk = 0; kk < 8; kk++) {
      float4 a0 = *(const float4*)&As[kk][tm4];
      float4 a1 = *(const float4*)&As[kk][64 + tm4];
      float4 b0 = *(const float4*)&Bs[kk][tn4];
      float4 b1 = *(const float4*)&Bs[kk][64 + tn4];
      float a[8] = {a0.x, a0.y, a0.z, a0.w, a1.x, a1.y, a1.z, a1.w};
      float b[8] = {b0.x, b0.y, b0.z, b0.w, b1.x, b1.y, b1.z, b1.w};
      #pragma unroll
      for (int i = 0; i < 8; i++)
        #pragma unroll
        for (int j = 0; j < 8; j++) acc[i][j] += a[i] * b[j];
    }
    __syncthreads();
  }
  #pragma unroll
  for (int i = 0; i < 8; i++) {
    int gm = bm + ((i < 4) ? (tm4 + i) : (64 + tm4 + i - 4));
    if (gm >= M) continue;
    #pragma unroll
    for (int j = 0; j < 8; j++) {
      int gn = bn + ((j < 4) ? (tn4 + j) : (64 + tn4 + j - 4));
      if (gn < N) C[(size_t)gm * N + gn] = acc[i][j] + (bias ? bias[gn] : 0.f);
    }
  }
}

// ---------------------------------------------------------------------------
// Prep: Wall = [WxF; WxB] (192x128), ball = [bxF; bxB]
// ---------------------------------------------------------------------------
__global__ __launch_bounds__(256) void k_prep(const float* __restrict__ WxF,
    const float* __restrict__ WxB, const float* __restrict__ bxF,
    const float* __restrict__ bxB,
    float* __restrict__ Wall, float* __restrict__ ball) {
  int i = blockIdx.x * 256 + threadIdx.x;
  if (i < 96 * 128) Wall[i] = WxF[i];
  else if (i < 192 * 128) Wall[i] = WxB[i - 96 * 128];
  if (i < 96) ball[i] = bxF[i];
  else if (i < 192) ball[i] = bxB[i - 96];
}

// ---------------------------------------------------------------------------
// Tree: per tree gather 15 rows of E', bottom-up subtree sums, node max with
// bias*subtree_count folded in. 2 trees per block.
// ---------------------------------------------------------------------------
__global__ __launch_bounds__(256) void k_tree(const int* __restrict__ ast,
    const float* __restrict__ Ep, const float* __restrict__ Wc_b,
    float* __restrict__ x) {
  int lt = threadIdx.x >> 7;      // 0/1
  int d  = threadIdx.x & 127;
  int tree = blockIdx.x * 2 + lt;
  __shared__ int toks[2][15];
  if (d < 15) toks[lt][d] = ast[(size_t)tree * 15 + d];
  __syncthreads();
  float e[15];
  #pragma unroll
  for (int n = 0; n < 15; n++) e[n] = Ep[(size_t)toks[lt][n] * 128 + d];
  float b = Wc_b[d];
  float s3 = e[3] + e[7] + e[8],  s4 = e[4] + e[9] + e[10];
  float s5 = e[5] + e[11] + e[12], s6 = e[6] + e[13] + e[14];
  float s1 = e[1] + s3 + s4, s2 = e[2] + s5 + s6;
  float s0 = e[0] + s1 + s2;
  float ml = fmaxf(fmaxf(fmaxf(e[7], e[8]), fmaxf(e[9], e[10])),
                   fmaxf(fmaxf(e[11], e[12]), fmaxf(e[13], e[14]))) + b;
  float mm = fmaxf(fmaxf(s3, s4), fmaxf(s5, s6)) + 3.f * b;
  float mt = fmaxf(s1, s2) + 7.f * b;
  float m = fmaxf(fmaxf(ml, mm), fmaxf(mt, s0 + 15.f * b));
  x[(size_t)tree * 128 + d] = m;
}

// ---------------------------------------------------------------------------
// GRU recurrence, one block per (sequence, direction). Hidden=32, gates=96.
// ---------------------------------------------------------------------------
__global__ __launch_bounds__(128) void k_gru(const float* __restrict__ xe_all,
    const float* __restrict__ WhF, const float* __restrict__ WhB,
    const float* __restrict__ bhF, const float* __restrict__ bhB,
    float* __restrict__ code) {
  int bsq = blockIdx.x >> 1, dir = blockIdx.x & 1;
  int g = threadIdx.x;
  __shared__ float whs[96 * 32];
  __shared__ float h_lds[32];
  __shared__ float rz[64];
  __shared__ float nn[32];
  const float* Wh = dir ? WhB : WhF;
  const float* bh = dir ? bhB : bhF;
  for (int i = g; i < 96 * 32; i += 128) whs[i] = Wh[i];
  if (g < 32) h_lds[g] = 0.f;
  __syncthreads();
  float w[32]; float bhv = 0.f, mxv = -1e30f;
  if (g < 96) {
    #pragma unroll
    for (int j = 0; j < 32; j++) w[j] = whs[g * 32 + j];
    bhv = bh[g];
  }
  for (int s = 0; s < 16; s++) {
    int t = dir ? (15 - s) : s;
    const float* xe = xe_all + ((size_t)(bsq * 16 + t)) * 192 + dir * 96;
    float gh = bhv, xv = 0.f;
    if (g < 96) {
      xv = xe[g];
      #pragma unroll
      for (int j = 0; j < 32; j++) gh += w[j] * h_lds[j];
    }
    if (g < 64) rz[g] = 1.f / (1.f + expf(-(xv + gh)));
    __syncthreads();
    if (g >= 64 && g < 96) nn[g - 64] = tanhf(xv + rz[g - 64] * gh);
    __syncthreads();
    if (g < 32) {
      float z = rz[g + 32];
      float hn = (1.f - z) * nn[g] + z * h_lds[g];
      mxv = fmaxf(mxv, hn);
      h_lds[g] = hn;
    }
    __syncthreads();
  }
  if (g < 32) code[(size_t)bsq * 64 + dir * 32 + g] = mxv;
}

// ---------------------------------------------------------------------------
// Build lin = [c_embed(101) | code(64) | cur_result(2)]
// ---------------------------------------------------------------------------
__global__ __launch_bounds__(256) void k_lin(const float* __restrict__ c_embed,
    const float* __restrict__ code, const float* __restrict__ cur,
    float* __restrict__ lin) {
  int i = blockIdx.x * 256 + threadIdx.x;
  if (i >= NROW * LIN_D) return;
  int row = i / LIN_D, j = i - row * LIN_D;
  float v;
  if (j < 101) v = c_embed[row * 101 + j];
  else if (j < 165) v = code[row * 64 + (j - 101)];
  else v = cur[row * 2 + (j - 165)];
  lin[i] = v;
}

// ---------------------------------------------------------------------------
// LSTM v4: 32 blocks x 512 threads (8 waves, 2/SIMD, 256-VGPR cap).
// Thread t owns gate row t: 32 float4 = 128 VGPRs, loaded ONCE via explicit
// global_load_dwordx4 inline asm (outputs can't be rematerialized/sunk).
// h broadcast: 2 ds_read_b32 per thread + v_readlane per k. Per step:
// ~256 VALU/thread -> ~1.1k cyc/step.
// ---------------------------------------------------------------------------
#define RL(v, l) __int_as_float(__builtin_amdgcn_readlane(__float_as_int(v), (l)))

__global__ __launch_bounds__(512, 2) void k_lstm(const float* __restrict__ xeL,
    const float* __restrict__ Wh, const float* __restrict__ bh,
    float* __restrict__ lout) {
  int b = blockIdx.x; int t = threadIdx.x;
  int lane = t & 63;
  __shared__ float hbuf[128];
  __shared__ float ga[512];
  // --- force-load this thread's weight row into 32 VGPR quads ---
  f32x4 w[32];
  const float* base = Wh + (size_t)t * 128;
  #pragma unroll
  for (int j = 0; j < 8; j++) {
    asm volatile("global_load_dwordx4 %0, %1, off offset:%2"
                 : "=v"(w[4*j+0]) : "v"(base), "i"(j*64+0));
    asm volatile("global_load_dwordx4 %0, %1, off offset:%2"
                 : "=v"(w[4*j+1]) : "v"(base), "i"(j*64+16));
    asm volatile("global_load_dwordx4 %0, %1, off offset:%2"
                 : "=v"(w[4*j+2]) : "v"(base), "i"(j*64+32));
    asm volatile("global_load_dwordx4 %0, %1, off offset:%2"
                 : "=v"(w[4*j+3]) : "v"(base), "i"(j*64+48));
  }
  asm volatile("s_waitcnt vmcnt(0)" ::: "memory");
  __builtin_amdgcn_sched_barrier(0);

  float bhv = bh[t];
  float c = 0.f;
  if (t < 128) hbuf[t] = 0.f;
  const float* xrow = xeL + (size_t)b * 50 * 512;
  float xe = xrow[t];                 // step-0 prefetch
  __syncthreads();
  for (int step = 0; step < 50; step++) {
    float h0 = hbuf[lane];
    float h1 = hbuf[64 + lane];
    float acc_a = xe + bhv, acc_b = 0.f;
    if (step < 49) xe = xrow[(size_t)(step + 1) * 512 + t];
    #pragma unroll
    for (int i = 0; i < 16; i++) {
      f32x4 a = w[i];
      acc_a += RL(h0, 4*i+0) * a.x;
      acc_b += RL(h0, 4*i+1) * a.y;
      acc_a += RL(h0, 4*i+2) * a.z;
      acc_b += RL(h0, 4*i+3) * a.w;
    }
    #pragma unroll
    for (int i = 0; i < 16; i++) {
      f32x4 a = w[16 + i];
      acc_a += RL(h1, 4*i+0) * a.x;
      acc_b += RL(h1, 4*i+1) * a.y;
      acc_a += RL(h1, 4*i+2) * a.z;
      acc_b += RL(h1, 4*i+3) * a.w;
    }
    ga[t] = acc_a + acc_b;
    __syncthreads();
    if (t < 128) {
      float iv = 1.f / (1.f + expf(-ga[t]));
      float fv = 1.f / (1.f + expf(-ga[t + 128]));
      float gv = tanhf(ga[t + 256]);
      float ov = 1.f / (1.f + expf(-ga[t + 384]));
      c = fv * c + iv * gv;
      float h = ov * tanhf(c);
      hbuf[t] = h;
      lout[((size_t)b * 50 + step) * 128 + t] = h;
    }
    __syncthreads();
  }
}

// ---------------------------------------------------------------------------
// Prediction head: p1 = lout . (pred_w^T tc) + tc . pred_b
// ---------------------------------------------------------------------------
__global__ __launch_bounds__(128) void k_pred(const float* __restrict__ lout,
    const float* __restrict__ pred_w, const float* __restrict__ pred_b,
    const float* __restrict__ tc, const float* __restrict__ result,
    float* __restrict__ out, float* __restrict__ fpbuf, float* __restrict__ mbuf) {
  int row = blockIdx.x; int k = threadIdx.x;
  __shared__ float tcs[101];
  __shared__ float r1[128], r2[128], r3[128];
  if (k < 101) tcs[k] = tc[(size_t)row * 101 + k];
  __syncthreads();
  float lk = lout[(size_t)row * 128 + k];
  float acc = 0.f;
  for (int c = 0; c < 101; c++) acc += tcs[c] * pred_w[c * 128 + k];
  float v = acc * lk;
  float pb = (k < 101) ? tcs[k] * pred_b[k] : 0.f;
  float nc = (k < 101) ? tcs[k] : 0.f;
  r1[k] = v; r2[k] = pb; r3[k] = nc;
  __syncthreads();
  for (int st = 64; st > 0; st >>= 1) {
    if (k < st) { r1[k] += r1[k + st]; r2[k] += r2[k + st]; r3[k] += r3[k + st]; }
    __syncthreads();
  }
  if (k == 0) {
    float ncon = r3[0];
    float m = (ncon > 0.f) ? 1.f : 0.f;
    float fp = (r1[0] + r2[0]) / fmaxf(ncon, 1.f);
    fpbuf[row] = fp; mbuf[row] = m;
    out[1 + row] = m / (1.f + expf(-fp));
    out[1 + NROW + row] = result[row] * m;
  }
}

// ---------------------------------------------------------------------------
// Loss reduction (single block, deterministic tree reduce)
// ---------------------------------------------------------------------------
__global__ __launch_bounds__(256) void k_loss(const float* __restrict__ fpbuf,
    const float* __restrict__ mbuf, const float* __restrict__ result,
    float* __restrict__ out) {
  __shared__ float sb[256], sm[256];
  int k = threadIdx.x;
  float ab = 0.f, am = 0.f;
  for (int r = k; r < NROW; r += 256) {
    float fp = fpbuf[r], m = mbuf[r], res = result[r];
    float bce = fmaxf(fp, 0.f) - fp * res + log1pf(expf(-fabsf(fp)));
    ab += bce * m; am += m;
  }
  sb[k] = ab; sm[k] = am;
  __syncthreads();
  for (int st = 128; st > 0; st >>= 1) {
    if (k < st) { sb[k] += sb[k + st]; sm[k] += sm[k + st]; }
    __syncthreads();
  }
  if (k == 0) out[0] = sb[0] / fmaxf(sm[0], 1.f);
}

// ---------------------------------------------------------------------------
extern "C" void kernel_launch(void* const* d_in, const int* in_sizes, int n_in,
                              void* d_out, int out_size, void* d_ws, size_t ws_size,
                              hipStream_t stream) {
  (void)in_sizes; (void)n_in; (void)out_size; (void)ws_size;
  const int*   ast      = (const int*)  d_in[2];
  const float* target_c = (const float*)d_in[3];
  const float* c_embed  = (const float*)d_in[4];
  const float* cur_res  = (const float*)d_in[5];
  const float* result   = (const float*)d_in[6];
  const float* emb      = (const float*)d_in[7];
  const float* Wc_w     = (const float*)d_in[8];
  const float* Wc_b     = (const float*)d_in[9];
  const float* gru_WxF  = (const float*)d_in[10];
  const float* gru_WhF  = (const float*)d_in[11];
  const float* gru_bxF  = (const float*)d_in[12];
  const float* gru_bhF  = (const float*)d_in[13];
  const float* gru_WxB  = (const float*)d_in[14];
  const float* gru_WhB  = (const float*)d_in[15];
  const float* gru_bxB  = (const float*)d_in[16];
  const float* gru_bhB  = (const float*)d_in[17];
  const float* lstm_Wx  = (const float*)d_in[18];
  const float* lstm_Wh  = (const float*)d_in[19];
  const float* lstm_bx  = (const float*)d_in[20];
  const float* lstm_bh  = (const float*)d_in[21];
  const float* pred_w   = (const float*)d_in[22];
  const float* pred_b   = (const float*)d_in[23];
  float* out = (float*)d_out;

  float* W = (float*)d_ws;
  float* Ep     = W;                 // 6,400,000 (VOCAB*128)
  float* xe_all = W;                 // alias: 25600*192 = 4,915,200 <= Ep size
  float* x      = W + 6400000;       // 3,276,800
  float* Wall   = W + 9676800;       // 24,576
  float* ball   = W + 9701376;       // 192
  float* code   = W + 9767104;       // 102,400
  float* lin    = W + 9869504;       // 267,200
  float* xeL    = W + 10136704;      // 819,200
  float* lout   = W + 10955904;      // 204,800
  float* fpbuf  = W + 11160704;      // 1,600
  float* mbuf   = W + 11162304;      // 1,600

  // 1. E' = emb @ Wc_w^T   (vocab-level projection)
  sgemm_nt<<<dim3(1, 391), 256, 0, stream>>>(emb, Wc_w, nullptr, Ep, VOCAB, 128, 128);
  // 2. weight prep
  k_prep<<<256, 256, 0, stream>>>(gru_WxF, gru_WxB, gru_bxF, gru_bxB, Wall, ball);
  // 3. tree gather/sum/max -> x (25600 x 128)
  k_tree<<<NTREE / 2, 256, 0, stream>>>(ast, Ep, Wc_b, x);
  // 4. xe_all = x @ Wall^T + ball  (25600 x 192)  [aliases Ep region]
  sgemm_nt<<<dim3(2, 200), 256, 0, stream>>>(x, Wall, ball, xe_all, NTREE, 192, 128);
  // 5. GRU recurrence + time max -> code (1600 x 64)
  k_gru<<<NROW * 2, 128, 0, stream>>>(xe_all, gru_WhF, gru_WhB, gru_bhF, gru_bhB, code);
  // 6. lin build (1600 x 167)
  k_lin<<<(NROW * LIN_D + 255) / 256, 256, 0, stream>>>(c_embed, code, cur_res, lin);
  // 7. xeL = lin @ lstm_Wx^T + lstm_bx (1600 x 512)
  sgemm_nt<<<dim3(4, 13), 256, 0, stream>>>(lin, lstm_Wx, lstm_bx, xeL, NROW, 512, LIN_D);
  // 8. LSTM recurrence -> lout (1600 x 128)  [asm-pinned register weights]
  k_lstm<<<BS, 512, 0, stream>>>(xeL, lstm_Wh, lstm_bh, lout);
  // 9. prediction head -> out[1..], fpbuf, mbuf
  k_pred<<<NROW, 128, 0, stream>>>(lout, pred_w, pred_b, target_c, result,
                                   out, fpbuf, mbuf);
  // 10. loss -> out[0]
  k_loss<<<1, 256, 0, stream>>>(fpbuf, mbuf, result, out);
}

// Round 5
// 246.628 us; speedup vs baseline: 1.7185x; 1.2891x over previous
//
#include <hip/hip_runtime.h>
#include <hip/hip_bf16.h>
#include <math.h>

// Problem constants
#define BS 32
#define SEQ 50
#define ML 16
#define NN 15
#define NTREE (BS*SEQ*ML)     // 25600
#define NROW (BS*SEQ)         // 1600
#define VOCAB 50000
#define EMB 128
#define ENC 128
#define GH 32
#define NC 100
#define LH 128
#define LIN_D 167             // 101 + 64 + 2

typedef float f32x4 __attribute__((ext_vector_type(4)));

// ---------------------------------------------------------------------------
// fp32 GEMM: C[M][N] = A[M][K] @ B[N][K]^T (+ bias[N])
// BM=64 x BN=128 tile, BK=32, 256 threads, 4x8 per thread.
// Coalesced float4 staging (8 lanes/row = 128B segments), k-major LDS with
// 16B-aligned strides so the inner loop is 3x ds_read_b128 + 32 v_fmac per kk.
// Grid ~3 blocks/CU for the big shapes (vs 1.5 before) -> latency hidden.
// ---------------------------------------------------------------------------
__global__ __launch_bounds__(256) void sgemm_nt(const float* __restrict__ A,
    const float* __restrict__ B, const float* __restrict__ bias,
    float* __restrict__ C, int M, int N, int K) {
  __shared__ float As[32][68];    // [k][m], stride 68: 16B-aligned, write 4-way max
  __shared__ float Bs[32][132];   // [k][n], stride 132: 16B-aligned
  const int bm = blockIdx.y * 64, bn = blockIdx.x * 128;
  const int tid = threadIdx.x;
  const int tm = (tid >> 4) << 2;   // 0..60 (row group of 4)
  const int tn = (tid & 15) << 3;   // 0..120 (col group of 8)
  const int srow = tid >> 3;        // 0..31 staging row
  const int q4 = (tid & 7) << 2;    // 0,4,..,28 staging k-quad
  const bool vec_ok = ((K & 3) == 0);

  float acc[4][8];
  #pragma unroll
  for (int i = 0; i < 4; i++)
    #pragma unroll
    for (int j = 0; j < 8; j++) acc[i][j] = 0.f;

  for (int k0 = 0; k0 < K; k0 += 32) {
    if (vec_ok && (k0 + 32 <= K)) {
      // A: rows srow, srow+32 (clamped), 16B coalesced
      #pragma unroll
      for (int h = 0; h < 2; h++) {
        int gm = bm + srow + h * 32;
        int rm = (gm < M) ? gm : (M - 1);
        float4 av = *(const float4*)&A[(size_t)rm * K + k0 + q4];
        As[q4 + 0][srow + h * 32] = av.x;
        As[q4 + 1][srow + h * 32] = av.y;
        As[q4 + 2][srow + h * 32] = av.z;
        As[q4 + 3][srow + h * 32] = av.w;
      }
      // B: rows srow + h*32, h=0..3
      #pragma unroll
      for (int h = 0; h < 4; h++) {
        int gn = bn + srow + h * 32;
        float4 bv = make_float4(0.f, 0.f, 0.f, 0.f);
        if (gn < N) bv = *(const float4*)&B[(size_t)gn * K + k0 + q4];
        Bs[q4 + 0][srow + h * 32] = bv.x;
        Bs[q4 + 1][srow + h * 32] = bv.y;
        Bs[q4 + 2][srow + h * 32] = bv.z;
        Bs[q4 + 3][srow + h * 32] = bv.w;
      }
    } else {
      // scalar guarded path (K not multiple of 4, or K tail)
      #pragma unroll
      for (int h = 0; h < 2; h++) {
        int gm = bm + srow + h * 32;
        int rm = (gm < M) ? gm : (M - 1);
        #pragma unroll
        for (int j = 0; j < 4; j++) {
          int gk = k0 + q4 + j;
          As[q4 + j][srow + h * 32] = (gk < K) ? A[(size_t)rm * K + gk] : 0.f;
        }
      }
      #pragma unroll
      for (int h = 0; h < 4; h++) {
        int gn = bn + srow + h * 32;
        #pragma unroll
        for (int j = 0; j < 4; j++) {
          int gk = k0 + q4 + j;
          Bs[q4 + j][srow + h * 32] =
              (gn < N && gk < K) ? B[(size_t)gn * K + gk] : 0.f;
        }
      }
    }
    __syncthreads();
    #pragma unroll
    for (int kk = 0; kk < 32; kk++) {
      float4 a4 = *(const float4*)&As[kk][tm];
      float4 b0 = *(const float4*)&Bs[kk][tn];
      float4 b1 = *(const float4*)&Bs[kk][tn + 4];
      float a[4] = {a4.x, a4.y, a4.z, a4.w};
      float b[8] = {b0.x, b0.y, b0.z, b0.w, b1.x, b1.y, b1.z, b1.w};
      #pragma unroll
      for (int i = 0; i < 4; i++)
        #pragma unroll
        for (int j = 0; j < 8; j++) acc[i][j] += a[i] * b[j];
    }
    __syncthreads();
  }

  // epilogue: float4 stores (all call-site N are multiples of 8)
  float bb[8];
  #pragma unroll
  for (int j = 0; j < 8; j++) {
    int gn = bn + tn + j;
    bb[j] = (bias && gn < N) ? bias[gn] : 0.f;
  }
  if (bn + tn < N) {
    #pragma unroll
    for (int i = 0; i < 4; i++) {
      int gm = bm + tm + i;
      if (gm >= M) continue;
      float4 v0 = make_float4(acc[i][0] + bb[0], acc[i][1] + bb[1],
                              acc[i][2] + bb[2], acc[i][3] + bb[3]);
      float4 v1 = make_float4(acc[i][4] + bb[4], acc[i][5] + bb[5],
                              acc[i][6] + bb[6], acc[i][7] + bb[7]);
      *(float4*)&C[(size_t)gm * N + bn + tn] = v0;
      *(float4*)&C[(size_t)gm * N + bn + tn + 4] = v1;
    }
  }
}

// ---------------------------------------------------------------------------
// Prep: Wall = [WxF; WxB] (192x128), ball = [bxF; bxB]
// ---------------------------------------------------------------------------
__global__ __launch_bounds__(256) void k_prep(const float* __restrict__ WxF,
    const float* __restrict__ WxB, const float* __restrict__ bxF,
    const float* __restrict__ bxB,
    float* __restrict__ Wall, float* __restrict__ ball) {
  int i = blockIdx.x * 256 + threadIdx.x;
  if (i < 96 * 128) Wall[i] = WxF[i];
  else if (i < 192 * 128) Wall[i] = WxB[i - 96 * 128];
  if (i < 96) ball[i] = bxF[i];
  else if (i < 192) ball[i] = bxB[i - 96];
}

// ---------------------------------------------------------------------------
// Tree: per tree gather 15 rows of E', bottom-up subtree sums, node max with
// bias*subtree_count folded in. 2 trees per block.
// ---------------------------------------------------------------------------
__global__ __launch_bounds__(256) void k_tree(const int* __restrict__ ast,
    const float* __restrict__ Ep, const float* __restrict__ Wc_b,
    float* __restrict__ x) {
  int lt = threadIdx.x >> 7;      // 0/1
  int d  = threadIdx.x & 127;
  int tree = blockIdx.x * 2 + lt;
  __shared__ int toks[2][15];
  if (d < 15) toks[lt][d] = ast[(size_t)tree * 15 + d];
  __syncthreads();
  float e[15];
  #pragma unroll
  for (int n = 0; n < 15; n++) e[n] = Ep[(size_t)toks[lt][n] * 128 + d];
  float b = Wc_b[d];
  float s3 = e[3] + e[7] + e[8],  s4 = e[4] + e[9] + e[10];
  float s5 = e[5] + e[11] + e[12], s6 = e[6] + e[13] + e[14];
  float s1 = e[1] + s3 + s4, s2 = e[2] + s5 + s6;
  float s0 = e[0] + s1 + s2;
  float ml = fmaxf(fmaxf(fmaxf(e[7], e[8]), fmaxf(e[9], e[10])),
                   fmaxf(fmaxf(e[11], e[12]), fmaxf(e[13], e[14]))) + b;
  float mm = fmaxf(fmaxf(s3, s4), fmaxf(s5, s6)) + 3.f * b;
  float mt = fmaxf(s1, s2) + 7.f * b;
  float m = fmaxf(fmaxf(ml, mm), fmaxf(mt, s0 + 15.f * b));
  x[(size_t)tree * 128 + d] = m;
}

// ---------------------------------------------------------------------------
// GRU recurrence, one block per (sequence, direction). Hidden=32, gates=96.
// ---------------------------------------------------------------------------
__global__ __launch_bounds__(128) void k_gru(const float* __restrict__ xe_all,
    const float* __restrict__ WhF, const float* __restrict__ WhB,
    const float* __restrict__ bhF, const float* __restrict__ bhB,
    float* __restrict__ code) {
  int bsq = blockIdx.x >> 1, dir = blockIdx.x & 1;
  int g = threadIdx.x;
  __shared__ float whs[96 * 32];
  __shared__ float h_lds[32];
  __shared__ float rz[64];
  __shared__ float nn[32];
  const float* Wh = dir ? WhB : WhF;
  const float* bh = dir ? bhB : bhF;
  for (int i = g; i < 96 * 32; i += 128) whs[i] = Wh[i];
  if (g < 32) h_lds[g] = 0.f;
  __syncthreads();
  float w[32]; float bhv = 0.f, mxv = -1e30f;
  if (g < 96) {
    #pragma unroll
    for (int j = 0; j < 32; j++) w[j] = whs[g * 32 + j];
    bhv = bh[g];
  }
  for (int s = 0; s < 16; s++) {
    int t = dir ? (15 - s) : s;
    const float* xe = xe_all + ((size_t)(bsq * 16 + t)) * 192 + dir * 96;
    float gh = bhv, xv = 0.f;
    if (g < 96) {
      xv = xe[g];
      #pragma unroll
      for (int j = 0; j < 32; j++) gh += w[j] * h_lds[j];
    }
    if (g < 64) rz[g] = 1.f / (1.f + expf(-(xv + gh)));
    __syncthreads();
    if (g >= 64 && g < 96) nn[g - 64] = tanhf(xv + rz[g - 64] * gh);
    __syncthreads();
    if (g < 32) {
      float z = rz[g + 32];
      float hn = (1.f - z) * nn[g] + z * h_lds[g];
      mxv = fmaxf(mxv, hn);
      h_lds[g] = hn;
    }
    __syncthreads();
  }
  if (g < 32) code[(size_t)bsq * 64 + dir * 32 + g] = mxv;
}

// ---------------------------------------------------------------------------
// Build lin = [c_embed(101) | code(64) | cur_result(2)]
// ---------------------------------------------------------------------------
__global__ __launch_bounds__(256) void k_lin(const float* __restrict__ c_embed,
    const float* __restrict__ code, const float* __restrict__ cur,
    float* __restrict__ lin) {
  int i = blockIdx.x * 256 + threadIdx.x;
  if (i >= NROW * LIN_D) return;
  int row = i / LIN_D, j = i - row * LIN_D;
  float v;
  if (j < 101) v = c_embed[row * 101 + j];
  else if (j < 165) v = code[row * 64 + (j - 101)];
  else v = cur[row * 2 + (j - 165)];
  lin[i] = v;
}

// ---------------------------------------------------------------------------
// LSTM v4: 32 blocks x 512 threads (8 waves, 2/SIMD, 256-VGPR cap).
// Thread t owns gate row t: 32 float4 = 128 VGPRs, loaded ONCE via explicit
// global_load_dwordx4 inline asm (outputs can't be rematerialized/sunk).
// h broadcast: 2 ds_read_b32 per thread + v_readlane per k.
// ---------------------------------------------------------------------------
#define RL(v, l) __int_as_float(__builtin_amdgcn_readlane(__float_as_int(v), (l)))

__global__ __launch_bounds__(512, 2) void k_lstm(const float* __restrict__ xeL,
    const float* __restrict__ Wh, const float* __restrict__ bh,
    float* __restrict__ lout) {
  int b = blockIdx.x; int t = threadIdx.x;
  int lane = t & 63;
  __shared__ float hbuf[128];
  __shared__ float ga[512];
  // --- force-load this thread's weight row into 32 VGPR quads ---
  f32x4 w[32];
  const float* base = Wh + (size_t)t * 128;
  #pragma unroll
  for (int j = 0; j < 8; j++) {
    asm volatile("global_load_dwordx4 %0, %1, off offset:%2"
                 : "=v"(w[4*j+0]) : "v"(base), "i"(j*64+0));
    asm volatile("global_load_dwordx4 %0, %1, off offset:%2"
                 : "=v"(w[4*j+1]) : "v"(base), "i"(j*64+16));
    asm volatile("global_load_dwordx4 %0, %1, off offset:%2"
                 : "=v"(w[4*j+2]) : "v"(base), "i"(j*64+32));
    asm volatile("global_load_dwordx4 %0, %1, off offset:%2"
                 : "=v"(w[4*j+3]) : "v"(base), "i"(j*64+48));
  }
  asm volatile("s_waitcnt vmcnt(0)" ::: "memory");
  __builtin_amdgcn_sched_barrier(0);

  float bhv = bh[t];
  float c = 0.f;
  if (t < 128) hbuf[t] = 0.f;
  const float* xrow = xeL + (size_t)b * 50 * 512;
  float xe = xrow[t];                 // step-0 prefetch
  __syncthreads();
  for (int step = 0; step < 50; step++) {
    float h0 = hbuf[lane];
    float h1 = hbuf[64 + lane];
    float acc_a = xe + bhv, acc_b = 0.f;
    if (step < 49) xe = xrow[(size_t)(step + 1) * 512 + t];
    #pragma unroll
    for (int i = 0; i < 16; i++) {
      f32x4 a = w[i];
      acc_a += RL(h0, 4*i+0) * a.x;
      acc_b += RL(h0, 4*i+1) * a.y;
      acc_a += RL(h0, 4*i+2) * a.z;
      acc_b += RL(h0, 4*i+3) * a.w;
    }
    #pragma unroll
    for (int i = 0; i < 16; i++) {
      f32x4 a = w[16 + i];
      acc_a += RL(h1, 4*i+0) * a.x;
      acc_b += RL(h1, 4*i+1) * a.y;
      acc_a += RL(h1, 4*i+2) * a.z;
      acc_b += RL(h1, 4*i+3) * a.w;
    }
    ga[t] = acc_a + acc_b;
    __syncthreads();
    if (t < 128) {
      float iv = 1.f / (1.f + expf(-ga[t]));
      float fv = 1.f / (1.f + expf(-ga[t + 128]));
      float gv = tanhf(ga[t + 256]);
      float ov = 1.f / (1.f + expf(-ga[t + 384]));
      c = fv * c + iv * gv;
      float h = ov * tanhf(c);
      hbuf[t] = h;
      lout[((size_t)b * 50 + step) * 128 + t] = h;
    }
    __syncthreads();
  }
}

// ---------------------------------------------------------------------------
// Prediction head: p1 = lout . (pred_w^T tc) + tc . pred_b
// ---------------------------------------------------------------------------
__global__ __launch_bounds__(128) void k_pred(const float* __restrict__ lout,
    const float* __restrict__ pred_w, const float* __restrict__ pred_b,
    const float* __restrict__ tc, const float* __restrict__ result,
    float* __restrict__ out, float* __restrict__ fpbuf, float* __restrict__ mbuf) {
  int row = blockIdx.x; int k = threadIdx.x;
  __shared__ float tcs[101];
  __shared__ float r1[128], r2[128], r3[128];
  if (k < 101) tcs[k] = tc[(size_t)row * 101 + k];
  __syncthreads();
  float lk = lout[(size_t)row * 128 + k];
  float acc = 0.f;
  for (int c = 0; c < 101; c++) acc += tcs[c] * pred_w[c * 128 + k];
  float v = acc * lk;
  float pb = (k < 101) ? tcs[k] * pred_b[k] : 0.f;
  float nc = (k < 101) ? tcs[k] : 0.f;
  r1[k] = v; r2[k] = pb; r3[k] = nc;
  __syncthreads();
  for (int st = 64; st > 0; st >>= 1) {
    if (k < st) { r1[k] += r1[k + st]; r2[k] += r2[k + st]; r3[k] += r3[k + st]; }
    __syncthreads();
  }
  if (k == 0) {
    float ncon = r3[0];
    float m = (ncon > 0.f) ? 1.f : 0.f;
    float fp = (r1[0] + r2[0]) / fmaxf(ncon, 1.f);
    fpbuf[row] = fp; mbuf[row] = m;
    out[1 + row] = m / (1.f + expf(-fp));
    out[1 + NROW + row] = result[row] * m;
  }
}

// ---------------------------------------------------------------------------
// Loss reduction (single block, deterministic tree reduce)
// ---------------------------------------------------------------------------
__global__ __launch_bounds__(256) void k_loss(const float* __restrict__ fpbuf,
    const float* __restrict__ mbuf, const float* __restrict__ result,
    float* __restrict__ out) {
  __shared__ float sb[256], sm[256];
  int k = threadIdx.x;
  float ab = 0.f, am = 0.f;
  for (int r = k; r < NROW; r += 256) {
    float fp = fpbuf[r], m = mbuf[r], res = result[r];
    float bce = fmaxf(fp, 0.f) - fp * res + log1pf(expf(-fabsf(fp)));
    ab += bce * m; am += m;
  }
  sb[k] = ab; sm[k] = am;
  __syncthreads();
  for (int st = 128; st > 0; st >>= 1) {
    if (k < st) { sb[k] += sb[k + st]; sm[k] += sm[k + st]; }
    __syncthreads();
  }
  if (k == 0) out[0] = sb[0] / fmaxf(sm[0], 1.f);
}

// ---------------------------------------------------------------------------
extern "C" void kernel_launch(void* const* d_in, const int* in_sizes, int n_in,
                              void* d_out, int out_size, void* d_ws, size_t ws_size,
                              hipStream_t stream) {
  (void)in_sizes; (void)n_in; (void)out_size; (void)ws_size;
  const int*   ast      = (const int*)  d_in[2];
  const float* target_c = (const float*)d_in[3];
  const float* c_embed  = (const float*)d_in[4];
  const float* cur_res  = (const float*)d_in[5];
  const float* result   = (const float*)d_in[6];
  const float* emb      = (const float*)d_in[7];
  const float* Wc_w     = (const float*)d_in[8];
  const float* Wc_b     = (const float*)d_in[9];
  const float* gru_WxF  = (const float*)d_in[10];
  const float* gru_WhF  = (const float*)d_in[11];
  const float* gru_bxF  = (const float*)d_in[12];
  const float* gru_bhF  = (const float*)d_in[13];
  const float* gru_WxB  = (const float*)d_in[14];
  const float* gru_WhB  = (const float*)d_in[15];
  const float* gru_bxB  = (const float*)d_in[16];
  const float* gru_bhB  = (const float*)d_in[17];
  const float* lstm_Wx  = (const float*)d_in[18];
  const float* lstm_Wh  = (const float*)d_in[19];
  const float* lstm_bx  = (const float*)d_in[20];
  const float* lstm_bh  = (const float*)d_in[21];
  const float* pred_w   = (const float*)d_in[22];
  const float* pred_b   = (const float*)d_in[23];
  float* out = (float*)d_out;

  float* W = (float*)d_ws;
  float* Ep     = W;                 // 6,400,000 (VOCAB*128)
  float* xe_all = W;                 // alias: 25600*192 = 4,915,200 <= Ep size
  float* x      = W + 6400000;       // 3,276,800
  float* Wall   = W + 9676800;       // 24,576
  float* ball   = W + 9701376;       // 192
  float* code   = W + 9767104;       // 102,400
  float* lin    = W + 9869504;       // 267,200
  float* xeL    = W + 10136704;      // 819,200
  float* lout   = W + 10955904;      // 204,800
  float* fpbuf  = W + 11160704;      // 1,600
  float* mbuf   = W + 11162304;      // 1,600

  // 1. E' = emb @ Wc_w^T   (vocab-level projection)
  sgemm_nt<<<dim3(1, 782), 256, 0, stream>>>(emb, Wc_w, nullptr, Ep, VOCAB, 128, 128);
  // 2. weight prep
  k_prep<<<256, 256, 0, stream>>>(gru_WxF, gru_WxB, gru_bxF, gru_bxB, Wall, ball);
  // 3. tree gather/sum/max -> x (25600 x 128)
  k_tree<<<NTREE / 2, 256, 0, stream>>>(ast, Ep, Wc_b, x);
  // 4. xe_all = x @ Wall^T + ball  (25600 x 192)  [aliases Ep region]
  sgemm_nt<<<dim3(2, 400), 256, 0, stream>>>(x, Wall, ball, xe_all, NTREE, 192, 128);
  // 5. GRU recurrence + time max -> code (1600 x 64)
  k_gru<<<NROW * 2, 128, 0, stream>>>(xe_all, gru_WhF, gru_WhB, gru_bhF, gru_bhB, code);
  // 6. lin build (1600 x 167)
  k_lin<<<(NROW * LIN_D + 255) / 256, 256, 0, stream>>>(c_embed, code, cur_res, lin);
  // 7. xeL = lin @ lstm_Wx^T + lstm_bx (1600 x 512)
  sgemm_nt<<<dim3(4, 25), 256, 0, stream>>>(lin, lstm_Wx, lstm_bx, xeL, NROW, 512, LIN_D);
  // 8. LSTM recurrence -> lout (1600 x 128)  [asm-pinned register weights]
  k_lstm<<<BS, 512, 0, stream>>>(xeL, lstm_Wh, lstm_bh, lout);
  // 9. prediction head -> out[1..], fpbuf, mbuf
  k_pred<<<NROW, 128, 0, stream>>>(lout, pred_w, pred_b, target_c, result,
                                   out, fpbuf, mbuf);
  // 10. loss -> out[0]
  k_loss<<<1, 256, 0, stream>>>(fpbuf, mbuf, result, out);
}